// Round 12
// baseline (54.945 us; speedup 1.0000x reference)
//
#include <hip/hip_runtime.h>

#define N 256
#define NN 65536

typedef __attribute__((ext_vector_type(8))) __bf16 bf16x8;
typedef __attribute__((ext_vector_type(4))) __bf16 bf16x4v;
typedef __attribute__((ext_vector_type(4))) float f32x4;

// ---- workspace layout (float offsets) ----
#define F_PART   0u         // [1024 blocks][64 bl][32 ml] yadj partials
#define F_CSPART 2097152u   // [8 mt][256 j][256 k] colsum partials (f32)
#define F_WSC    2621440u   // [256]
#define F_CSB    2621696u   // 65536 bf16 (32768 floats): CS[j][k]
#define F_SFULL  2654464u   // [65536] f32
#define F_YADJ   2720000u   // [65536] f32
#define WS_FLOATS 2785536u

static __device__ __forceinline__ f32x4 mfma16(bf16x8 a, bf16x8 b, f32x4 c) {
  return __builtin_amdgcn_mfma_f32_16x16x32_bf16(a, b, c, 0, 0, 0);
}
static __device__ __forceinline__ bf16x4v pack4(float4 v) {
  bf16x4v r;
  r[0] = (__bf16)v.x; r[1] = (__bf16)v.y; r[2] = (__bf16)v.z; r[3] = (__bf16)v.w;
  return r;
}
static __device__ __forceinline__ bf16x8 pack8(float4 a, float4 b) {
  bf16x8 r;
  r[0] = (__bf16)a.x; r[1] = (__bf16)a.y; r[2] = (__bf16)a.z; r[3] = (__bf16)a.w;
  r[4] = (__bf16)b.x; r[5] = (__bf16)b.y; r[6] = (__bf16)b.z; r[7] = (__bf16)b.w;
  return r;
}

#define BARL()                                                            \
  asm volatile("s_waitcnt lgkmcnt(0)" ::: "memory");                      \
  __builtin_amdgcn_s_barrier();                                           \
  __builtin_amdgcn_sched_barrier(0);

// ============================================================================
// kbig v12: v11 with ONE change — NO GLOBAL STORES IN THE LOOP.
//   The CS cross-wave sums accumulate into 8 named registers (cv0..cv7,
//   static indexing) and are written to CSPART only in the epilogue.
//   vmcnt thus counts ONLY the clw loads inside the loop (kabl<3>
//   conditions): stores can no longer force per-tile vmcnt(0) drains.
// grid 1024 = 4 bh x 8 mt x 32 s; 256 thr (4 waves x 16 b-rows).
// LDS: 2 bufs x 16KB @0 | csl 2x4KB @32768 | xl[8][64]f32 @40960
//      (43008 B; wsc 'red' 8KB reuses buf region post-loop)
// ============================================================================
__global__ void __launch_bounds__(256) kbig(
    const float* __restrict__ X, const float* __restrict__ ctx,
    const float* __restrict__ W, const float* __restrict__ clb,
    const float* __restrict__ clw, float* __restrict__ ws)
{
  extern __shared__ char smem[];
  float* csl = (float*)(smem + 32768);
  float* xl  = (float*)(smem + 40960);
  float* red = (float*)smem;
  const int t = threadIdx.x;
  const int bh = blockIdx.x >> 8;          // 0..3
  const int rem = blockIdx.x & 255;
  const int mt = rem >> 5, s = rem & 31;
  const int n0 = s * 8, m0g = mt * 32, b0g = bh * 64;

  const int lane = t & 63, w = t >> 6;
  const int wb = w * 16;
  const int l15 = lane & 15, lhi = lane >> 4;
  const int swz = (l15 & 7) << 4;
  const float4* clwf4 = (const float4*)clw;

  // prologue: ctx -> af (32 VGPRs), X -> xl
  bf16x8 af[8];
#pragma unroll
  for (int c = 0; c < 8; ++c) {
    const float4* p = (const float4*)(ctx + (b0g + wb + l15) * N +
                                      c * 32 + lhi * 8);
    af[c] = pack8(p[0], p[1]);
  }
  if (t < 64) {
    const float4* xp = (const float4*)(X + (b0g + t) * N + n0);
    const float4 x0 = xp[0], x1 = xp[1];
    xl[0 * 64 + t] = x0.x; xl[1 * 64 + t] = x0.y;
    xl[2 * 64 + t] = x0.z; xl[3 * 64 + t] = x0.w;
    xl[4 * 64 + t] = x1.x; xl[5 * 64 + t] = x1.y;
    xl[6 * 64 + t] = x1.z; xl[7 * 64 + t] = x1.w;
  }

  const f32x4 zero = {0.f, 0.f, 0.f, 0.f};
  f32x4 acc[2];
  acc[0] = zero; acc[1] = zero;
  float cv0 = 0.f, cv1 = 0.f, cv2 = 0.f, cv3 = 0.f;
  float cv4 = 0.f, cv5 = 0.f, cv6 = 0.f, cv7 = 0.f;

#define STAGE(TT)                                                           \
  {                                                                         \
    float4 r[8];                                                            \
    _Pragma("unroll")                                                       \
    for (int i = 0; i < 8; ++i) {                                           \
      const int rowl = w * 8 + i;                                           \
      r[i] = clwf4[(size_t)((m0g + rowl) * 256 + n0 + (TT)) * 64 + lane];   \
    }                                                                       \
    _Pragma("unroll")                                                       \
    for (int i = 0; i < 8; ++i) {                                           \
      const int rowl = w * 8 + i;                                           \
      *(bf16x4v*)(smem + ((TT) & 1) * 16384 + rowl * 512 +                  \
                  ((lane * 8) ^ ((rowl & 7) << 4))) = pack4(r[i]);          \
    }                                                                       \
    if (bh == 0) {                                                          \
      float4 cso = r[0];                                                    \
      _Pragma("unroll")                                                     \
      for (int i = 1; i < 8; ++i) {                                         \
        cso.x += r[i].x; cso.y += r[i].y;                                   \
        cso.z += r[i].z; cso.w += r[i].w;                                   \
      }                                                                     \
      *(float4*)(csl + ((TT) & 1) * 1024 + w * 256 + lane * 4) = cso;       \
    }                                                                       \
    BARL();                                                                 \
  }

// COMP: MFMA + yadj fmacs + CS reg-accumulate (NO global stores)
#define COMP(NNV)                                                           \
  {                                                                         \
    const char* buf = smem + ((NNV) & 1) * 16384;                           \
    f32x4 h[2];                                                             \
    h[0] = zero; h[1] = zero;                                               \
    _Pragma("unroll")                                                       \
    for (int c = 0; c < 8; ++c) {                                           \
      const int kb = c * 64 + lhi * 16;                                     \
      bf16x8 b0 = *(const bf16x8*)(buf + l15 * 512 + (kb ^ swz));           \
      bf16x8 b1 = *(const bf16x8*)(buf + (16 + l15) * 512 + (kb ^ swz));    \
      h[0] = mfma16(af[c], b0, h[0]);                                       \
      h[1] = mfma16(af[c], b1, h[1]);                                       \
    }                                                                       \
    _Pragma("unroll")                                                       \
    for (int r = 0; r < 4; ++r) {                                           \
      const float xv = xl[(NNV) * 64 + wb + lhi * 4 + r];                   \
      acc[0][r] += xv * h[0][r];                                            \
      acc[1][r] += xv * h[1][r];                                            \
    }                                                                       \
    if (bh == 0) {                                                          \
      const int cb = ((NNV) & 1) * 1024;                                    \
      cv##NNV = csl[cb + t] + csl[cb + 256 + t] +                           \
                csl[cb + 512 + t] + csl[cb + 768 + t];                      \
    }                                                                       \
  }

  STAGE(0) COMP(0)
  STAGE(1) COMP(1)
  STAGE(2) COMP(2)
  STAGE(3) COMP(3)
  STAGE(4) COMP(4)
  STAGE(5) COMP(5)
  STAGE(6) COMP(6)
  STAGE(7) COMP(7)
#undef STAGE
#undef COMP

  // CS partials (epilogue, coalesced 1KB per tile-slot)
  if (bh == 0) {
    const size_t cbase = F_CSPART + mt * 65536u + (size_t)n0 * 256 + t;
    ws[cbase + 0 * 256] = cv0;
    ws[cbase + 1 * 256] = cv1;
    ws[cbase + 2 * 256] = cv2;
    ws[cbase + 3 * 256] = cv3;
    ws[cbase + 4 * 256] = cv4;
    ws[cbase + 5 * 256] = cv5;
    ws[cbase + 6 * 256] = cv6;
    ws[cbase + 7 * 256] = cv7;
  }

  // yadj partials: [block][64 bl][32 ml] (coalesced)
  const int base = blockIdx.x * 2048;
#pragma unroll
  for (int fm = 0; fm < 2; ++fm)
#pragma unroll
    for (int r = 0; r < 4; ++r)
      ws[F_PART + base + (wb + lhi * 4 + r) * 32 + fm * 16 + l15] =
          acc[fm][r];

  // wsc: colsum of W+CB for 8 j-columns, by (mt==0,bh==0) blocks
  if (mt == 0 && bh == 0) {
    __syncthreads();
    const float4* wp = (const float4*)(W + t * N + s * 8);
    const float4* cp = (const float4*)(clb + t * N + s * 8);
    const float4 a0 = wp[0], a1 = wp[1], c0 = cp[0], c1 = cp[1];
    red[0 * 256 + t] = a0.x + c0.x; red[1 * 256 + t] = a0.y + c0.y;
    red[2 * 256 + t] = a0.z + c0.z; red[3 * 256 + t] = a0.w + c0.w;
    red[4 * 256 + t] = a1.x + c1.x; red[5 * 256 + t] = a1.y + c1.y;
    red[6 * 256 + t] = a1.z + c1.z; red[7 * 256 + t] = a1.w + c1.w;
    __syncthreads();
    if (t < 64) {
      const int jj = t >> 3, seg = t & 7;
      float v = 0.f;
#pragma unroll
      for (int i = 0; i < 32; ++i) v += red[jj * 256 + seg * 32 + i];
      v += __shfl_xor(v, 1);
      v += __shfl_xor(v, 2);
      v += __shfl_xor(v, 4);
      if (seg == 0) ws[F_WSC + s * 8 + jj] = v;
    }
  }
}

// ============================================================================
// kred: yadj = sum over s-chunks; CS[j][k] = sum_mt CSPART -> bf16 CSB
// ============================================================================
__global__ void __launch_bounds__(256) kred(float* __restrict__ ws)
{
  const int o = blockIdx.x * 256 + threadIdx.x;
  const int b = o >> 8, col = o & 255;
  const int mt = col >> 5, ml = col & 31;
  const int bhh = b >> 6, bl = b & 63;
  float y = 0.f;
#pragma unroll
  for (int si = 0; si < 32; ++si)
    y += ws[F_PART + (size_t)(bhh * 256 + mt * 32 + si) * 2048 + bl * 32 + ml];
  ws[F_YADJ + o] = y;
  float cv = 0.f;
#pragma unroll
  for (int q = 0; q < 8; ++q)
    cv += ws[F_CSPART + q * 65536u + o];
  ((__bf16*)(ws + F_CSB))[o] = (__bf16)cv;
}

// ============================================================================
// kred2: SF[b,j] = wsc[j] + sum_k ctx[b,k]*CS[j,k]  (64 blocks, LDS-free)
// ============================================================================
__global__ void __launch_bounds__(256) kred2(
    const float* __restrict__ ctx, float* __restrict__ ws)
{
  const int t = threadIdx.x, blk = blockIdx.x;
  const int b0 = (blk >> 3) * 32, j0 = (blk & 7) * 32;
  const int lane = t & 63, w = t >> 6;
  const int l15 = lane & 15, lhi = lane >> 4;
  const int wqb = (w >> 1) * 16, wqj = (w & 1) * 16;
  const char* csb = (const char*)(ws + F_CSB);

  f32x4 accq = {0.f, 0.f, 0.f, 0.f};
#pragma unroll
  for (int c = 0; c < 8; ++c) {
    const float4* p = (const float4*)(ctx + (b0 + wqb + l15) * N +
                                      c * 32 + lhi * 8);
    bf16x8 a = pack8(p[0], p[1]);
    bf16x8 b = *(const bf16x8*)(csb + (j0 + wqj + l15) * 512 +
                                c * 64 + lhi * 16);
    accq = mfma16(a, b, accq);
  }
  const int j = j0 + wqj + l15;
  const float wscv = ws[F_WSC + j];
#pragma unroll
  for (int r = 0; r < 4; ++r) {
    const int b = b0 + wqb + lhi * 4 + r;
    ws[F_SFULL + b * N + j] = accq[r] + wscv;
  }
}

// ============================================================================
// kfin: unchanged (64 blocks, 2 fused K=256 MFMA chains + epilogue)
// ============================================================================
__global__ void __launch_bounds__(256) kfin(
    const float* __restrict__ X, const float* __restrict__ ctx,
    const float* __restrict__ W, const float* __restrict__ clb,
    const float* __restrict__ A, const float* __restrict__ scale,
    const int* __restrict__ tptr, float* __restrict__ out,
    float* __restrict__ ws)
{
  extern __shared__ char smem[];
  const int t = threadIdx.x, blk = blockIdx.x;
  const int b0 = (blk >> 3) * 32, k0 = (blk & 7) * 32;
  {
    const int row = t >> 3, q = t & 7;
    const int sw = (row & 7) << 4;
    const float4* sp = (const float4*)(ws + F_SFULL + (b0 + row) * N);
    const float4* xp = (const float4*)(X + (b0 + row) * N);
    const float4* wp = (const float4*)(W + (k0 + row) * N);
    const float4* cp = (const float4*)(clb + (k0 + row) * N);
#pragma unroll
    for (int i = 0; i < 8; ++i) {
      const int f4 = q * 8 + i;
      const int off = row * 512 + ((f4 * 8) ^ sw);
      *(bf16x4v*)(smem + off) = pack4(sp[f4]);
      *(bf16x4v*)(smem + 16384 + off) = pack4(xp[f4]);
      const float4 wv = wp[f4], cv = cp[f4];
      float4 s2;
      s2.x = wv.x + cv.x; s2.y = wv.y + cv.y;
      s2.z = wv.z + cv.z; s2.w = wv.w + cv.w;
      *(bf16x4v*)(smem + 49152 + off) = pack4(s2);
    }
    const float4* ap = (const float4*)(A + t * N + k0);
    char* at = smem + 32768;
#pragma unroll
    for (int i = 0; i < 8; ++i) {
      const float4 v = ap[i];
      const int kk = i * 4;
      *(__bf16*)(at + (kk + 0) * 512 + ((t * 2) ^ (((kk + 0) & 7) << 4))) = (__bf16)v.x;
      *(__bf16*)(at + (kk + 1) * 512 + ((t * 2) ^ (((kk + 1) & 7) << 4))) = (__bf16)v.y;
      *(__bf16*)(at + (kk + 2) * 512 + ((t * 2) ^ (((kk + 2) & 7) << 4))) = (__bf16)v.z;
      *(__bf16*)(at + (kk + 3) * 512 + ((t * 2) ^ (((kk + 3) & 7) << 4))) = (__bf16)v.w;
    }
  }
  __syncthreads();
  const int lane = t & 63, w = t >> 6;
  const int l15 = lane & 15, lhi = lane >> 4;
  const int wqb = (w >> 1) * 16, wqk = (w & 1) * 16;
  const int swz = (l15 & 7) << 4;
  f32x4 accd = {0.f, 0.f, 0.f, 0.f}, accw = {0.f, 0.f, 0.f, 0.f};
#pragma unroll
  for (int c = 0; c < 8; ++c) {
    const int kb = c * 64 + lhi * 16;
    bf16x8 as  = *(const bf16x8*)(smem + (wqb + l15) * 512 + (kb ^ swz));
    bf16x8 aat = *(const bf16x8*)(smem + 32768 + (wqk + l15) * 512 + (kb ^ swz));
    bf16x8 ax  = *(const bf16x8*)(smem + 16384 + (wqb + l15) * 512 + (kb ^ swz));
    bf16x8 awc = *(const bf16x8*)(smem + 49152 + (wqk + l15) * 512 + (kb ^ swz));
    accd = mfma16(as, aat, accd);
    accw = mfma16(ax, awc, accw);
  }
  const float sc = scale[0];
  const float tf = (float)(*tptr);
  const float c1 = tf / (tf + 1.f), c2 = 1.f / (tf + 1.f);
#pragma unroll
  for (int r = 0; r < 4; ++r) {
    const int b = b0 + wqb + lhi * 4 + r, k = k0 + wqk + l15;
    const int idx = b * N + k;
    const float xv = X[idx];
    out[idx] = sc * (xv * accd[r] - accw[r] - ws[F_YADJ + idx]);
    out[NN + idx] = ctx[idx] * c1 + xv * c2;
  }
}

extern "C" void kernel_launch(void* const* d_in, const int* in_sizes, int n_in,
                              void* d_out, int out_size, void* d_ws, size_t ws_size,
                              hipStream_t stream)
{
  (void)in_sizes; (void)n_in; (void)out_size;
  const float* X     = (const float*)d_in[0];
  const float* ctx   = (const float*)d_in[1];
  const float* W     = (const float*)d_in[2];
  const float* scale = (const float*)d_in[3];
  const float* A     = (const float*)d_in[4];
  const float* clw   = (const float*)d_in[5];
  const float* clb   = (const float*)d_in[6];
  const int*   tptr  = (const int*)d_in[7];
  float* out = (float*)d_out;
  float* ws  = (float*)d_ws;

  if (ws_size < (size_t)WS_FLOATS * sizeof(float)) return;

  (void)hipFuncSetAttribute((const void*)kbig,
                            hipFuncAttributeMaxDynamicSharedMemorySize, 43008);
  (void)hipFuncSetAttribute((const void*)kfin,
                            hipFuncAttributeMaxDynamicSharedMemorySize, 65536);

  kbig<<<1024, 256, 43008, stream>>>(X, ctx, W, clb, clw, ws);
  kred<<<256, 256, 0, stream>>>(ws);
  kred2<<<64, 256, 0, stream>>>(ctx, ws);
  kfin<<<64, 256, 65536, stream>>>(X, ctx, W, clb, A, scale, tptr, out, ws);
}